// Round 1
// baseline (343.822 us; speedup 1.0000x reference)
//
#include <hip/hip_runtime.h>

// ---------------- problem constants ----------------
#define T_LEN   2048
#define BATCH   2
#define DMODEL  1024
#define NHEAD   16
#define DHEAD   64
#define MROWS   4096          // T*B
#define KDIM    1024
#define NDIM    1024
#define ATT_SC2 (0.125f * 1.44269504088896f)   // SCALE * log2(e)

typedef unsigned short u16;
typedef unsigned int   u32;
typedef u16   u16x8 __attribute__((ext_vector_type(8)));
typedef u16   u16x4 __attribute__((ext_vector_type(4)));
typedef __bf16 bf16x8 __attribute__((ext_vector_type(8)));
typedef float f32x4 __attribute__((ext_vector_type(4)));

__device__ __forceinline__ u16 f2bf(float f) {
  u32 u = __builtin_bit_cast(u32, f);
  u += 0x7fffu + ((u >> 16) & 1u);           // round-to-nearest-even
  return (u16)(u >> 16);
}

__device__ __forceinline__ f32x4 mfma16(u16x8 a, u16x8 b, f32x4 c) {
  return __builtin_amdgcn_mfma_f32_16x16x32_bf16(
      __builtin_bit_cast(bf16x8, a), __builtin_bit_cast(bf16x8, b), c, 0, 0, 0);
}

__device__ __forceinline__ void gload16(const u16* g, u16* l) {
  // async global->LDS, 16B per lane; LDS dest = wave-uniform base + lane*16
  __builtin_amdgcn_global_load_lds((const __attribute__((address_space(1))) void*)g,
                                   (__attribute__((address_space(3))) void*)l,
                                   16, 0, 0);
}

// ---------------- cast f32 -> bf16 ----------------
// ws layout (u16 elems): [xb 4M][Wkb 1M][Wvb 1M][Wqb 1M][Wob 1M][Qh 4M][Kh 4M][Vt 4M][Aout 4M]
#define XN 4194304u
__global__ __launch_bounds__(256) void cast_all(
    const float* __restrict__ x,  const float* __restrict__ wk,
    const float* __restrict__ wv, const float* __restrict__ wq,
    const float* __restrict__ wo, u16* __restrict__ dst) {
  size_t i = ((size_t)blockIdx.x * 256 + threadIdx.x) * 4;
  const float* src; size_t off;
  if (i < XN) { src = x; off = i; }
  else {
    size_t t = i - XN;
    int wi = (int)(t >> 20);
    off = t & 1048575u;
    src = (wi == 0) ? wk : (wi == 1) ? wv : (wi == 2) ? wq : wo;
  }
  float4 v = *reinterpret_cast<const float4*>(src + off);
  u16x4 o;
  o.s0 = f2bf(v.x); o.s1 = f2bf(v.y); o.s2 = f2bf(v.z); o.s3 = f2bf(v.w);
  *reinterpret_cast<u16x4*>(dst + i) = o;
}

// ---------------- bf16 GEMM: C[M,N] = A[M,K] * W[N,K]^T ----------------
// 128x128 tile, BK=64, 4 waves (2x2), 4x4 accs of 16x16x32 MFMA per wave.
// epi==2 : plain f32 store to dst (row*NDIM+col)
// epi==0 : z=0/1 -> head scatter  [(b*16+h)][t][dp]   (col = dp*16+h, row = t*2+b)
//          z=2   -> V^T scatter   [(b*16+h)][dp][t]
__global__ __launch_bounds__(256) void gemm_bt(
    const u16* __restrict__ A,
    const u16* __restrict__ W0, const u16* __restrict__ W1, const u16* __restrict__ W2,
    void* dst0, void* dst1, void* dst2, int epi) {
  __shared__ __align__(16) u16 As[128 * 64];
  __shared__ __align__(16) u16 Bs[128 * 64];

  const int tid = threadIdx.x;
  const int l  = tid & 63, w = tid >> 6;
  const int lr = l & 15,  lg = l >> 4;
  const int wm = w >> 1,  wn = w & 1;
  const int z  = blockIdx.z;
  const u16* W = (z == 0) ? W0 : (z == 1) ? W1 : W2;
  void* dst    = (z == 0) ? dst0 : (z == 1) ? dst1 : dst2;
  const int m0 = blockIdx.y * 128;
  const int n0 = blockIdx.x * 128;

  f32x4 acc[4][4];
#pragma unroll
  for (int i = 0; i < 4; ++i)
#pragma unroll
    for (int j = 0; j < 4; ++j) acc[i][j] = (f32x4)(0.0f);

  for (int k0 = 0; k0 < KDIM; k0 += 64) {
    // stage A and B tiles (128 rows x 64 bf16 each), XOR-swizzled chunks:
    // logical (row r, 16B-chunk c) lives at physical chunk c ^ (r&7)
#pragma unroll
    for (int i = 0; i < 4; ++i) {
      int p  = i * 256 + tid;
      int r  = p >> 3, cph = p & 7;
      int cl = cph ^ (r & 7);
      u16* ldsA = As + (size_t)(i * 256 + w * 64) * 8;   // wave-uniform base
      u16* ldsB = Bs + (size_t)(i * 256 + w * 64) * 8;
      gload16(A + (size_t)(m0 + r) * KDIM + k0 + cl * 8, ldsA);
      gload16(W + (size_t)(n0 + r) * KDIM + k0 + cl * 8, ldsB);
    }
    __syncthreads();

#pragma unroll
    for (int ks = 0; ks < 2; ++ks) {
      u16x8 af[4], bf_[4];
      const int cr = ks * 4 + lg;
#pragma unroll
      for (int mi = 0; mi < 4; ++mi) {
        int rr = wm * 64 + mi * 16 + lr;
        af[mi] = *reinterpret_cast<const u16x8*>(As + rr * 64 + ((cr ^ (rr & 7)) * 8));
      }
#pragma unroll
      for (int ni = 0; ni < 4; ++ni) {
        int rr = wn * 64 + ni * 16 + lr;
        bf_[ni] = *reinterpret_cast<const u16x8*>(Bs + rr * 64 + ((cr ^ (rr & 7)) * 8));
      }
#pragma unroll
      for (int mi = 0; mi < 4; ++mi)
#pragma unroll
        for (int ni = 0; ni < 4; ++ni)
          acc[mi][ni] = mfma16(af[mi], bf_[ni], acc[mi][ni]);
    }
    __syncthreads();
  }

  const int mode = (epi == 2) ? 2 : ((z == 2) ? 1 : 0);
#pragma unroll
  for (int mi = 0; mi < 4; ++mi)
#pragma unroll
    for (int ni = 0; ni < 4; ++ni)
#pragma unroll
      for (int r = 0; r < 4; ++r) {
        int row = m0 + wm * 64 + mi * 16 + lg * 4 + r;   // C: row=(l>>4)*4+reg
        int col = n0 + wn * 64 + ni * 16 + lr;           //    col=l&15
        float v = acc[mi][ni][r];
        if (mode == 2) {
          ((float*)dst)[(size_t)row * NDIM + col] = v;
        } else {
          int t  = row >> 1, bb = row & 1;
          int dp = col >> 4, hh = col & 15;
          u16* d = (u16*)dst;
          if (mode == 0)
            d[((size_t)(bb * NHEAD + hh) * T_LEN + t) * DHEAD + dp] = f2bf(v);
          else
            d[((size_t)(bb * NHEAD + hh) * DHEAD + dp) * T_LEN + t] = f2bf(v);
        }
      }
}

// ---------------- causal flash attention ----------------
// grid (32 q-blocks, 32 bh). 4 waves/block, each wave owns 16 q-rows.
// Qh,Kh: [bh][t][64] bf16 ; Vt: [bh][64][t] bf16 ; Aout: [t*2+b][h*64+dp] bf16
__global__ __launch_bounds__(256) void attn_fwd(
    const u16* __restrict__ Qh, const u16* __restrict__ Kh,
    const u16* __restrict__ Vt, u16* __restrict__ Aout) {
  __shared__ __align__(16) u16 Plds[4][16 * 48];

  const int tid = threadIdx.x;
  const int l = tid & 63, w = tid >> 6;
  const int lr = l & 15, lg = l >> 4;
  const int qb = blockIdx.x, bh = blockIdx.y;
  const int b = bh >> 4, h = bh & 15;
  const int qbase = qb * 64 + w * 16;
  u16* pl = &Plds[w][0];

  // Q fragments (hoisted): A-frag row = lr, k(d) = lg*8+j (+32 for second half)
  const u16* qptr = Qh + ((size_t)bh * T_LEN + qbase + lr) * DHEAD + lg * 8;
  const u16x8 qf0 = *reinterpret_cast<const u16x8*>(qptr);
  const u16x8 qf1 = *reinterpret_cast<const u16x8*>(qptr + 32);

  const u16* kbase = Kh + (size_t)bh * T_LEN * DHEAD;
  const u16* vbase = Vt + (size_t)bh * DHEAD * T_LEN;

  f32x4 oacc[4];
#pragma unroll
  for (int i = 0; i < 4; ++i) oacc[i] = (f32x4)(0.0f);
  float m_[4] = {-1e30f, -1e30f, -1e30f, -1e30f};
  float s_[4] = {0.f, 0.f, 0.f, 0.f};

  const int qmax = qbase + 15;
  for (int kv0 = 0; kv0 <= qmax; kv0 += 32) {
    // S = Q K^T for kv columns [kv0, kv0+32)
    const u16* kp0 = kbase + (size_t)(kv0 + lr) * DHEAD + lg * 8;
    const u16* kp1 = kp0 + 16 * DHEAD;
    u16x8 k00 = *reinterpret_cast<const u16x8*>(kp0);
    u16x8 k01 = *reinterpret_cast<const u16x8*>(kp0 + 32);
    u16x8 k10 = *reinterpret_cast<const u16x8*>(kp1);
    u16x8 k11 = *reinterpret_cast<const u16x8*>(kp1 + 32);
    f32x4 s0 = (f32x4)(0.0f), s1 = (f32x4)(0.0f);
    s0 = mfma16(qf0, k00, s0); s0 = mfma16(qf1, k01, s0);
    s1 = mfma16(qf0, k10, s1); s1 = mfma16(qf1, k11, s1);

#pragma unroll
    for (int r = 0; r < 4; ++r) {
      const int q_idx = qbase + lg * 4 + r;
      float a0 = (kv0 + lr      <= q_idx) ? s0[r] * ATT_SC2 : -1e30f;
      float a1 = (kv0 + 16 + lr <= q_idx) ? s1[r] * ATT_SC2 : -1e30f;
      float v = fmaxf(a0, a1);
      v = fmaxf(v, __shfl_xor(v, 1, 64));
      v = fmaxf(v, __shfl_xor(v, 2, 64));
      v = fmaxf(v, __shfl_xor(v, 4, 64));
      v = fmaxf(v, __shfl_xor(v, 8, 64));
      const float mnew = fmaxf(m_[r], v);
      const float al = __builtin_amdgcn_exp2f(m_[r] - mnew);
      const float p0 = __builtin_amdgcn_exp2f(a0 - mnew);
      const float p1 = __builtin_amdgcn_exp2f(a1 - mnew);
      float rs = p0 + p1;
      rs += __shfl_xor(rs, 1, 64);
      rs += __shfl_xor(rs, 2, 64);
      rs += __shfl_xor(rs, 4, 64);
      rs += __shfl_xor(rs, 8, 64);
      s_[r] = s_[r] * al + rs;
      m_[r] = mnew;
      oacc[0][r] *= al; oacc[1][r] *= al; oacc[2][r] *= al; oacc[3][r] *= al;
      const int row = lg * 4 + r;            // C-layout row of S/P
      pl[row * 48 + lr]      = f2bf(p0);     // P col = tile*16 + lr
      pl[row * 48 + 16 + lr] = f2bf(p1);
    }

    // PV: A-frag of P (row=lr, k=lg*8+j) read back from LDS (wave-local)
    u16x8 pa = *reinterpret_cast<const u16x8*>(pl + lr * 48 + lg * 8);
    const u16* vp = vbase + kv0 + lg * 8;
#pragma unroll
    for (int ni = 0; ni < 4; ++ni) {
      u16x8 vf = *reinterpret_cast<const u16x8*>(vp + (size_t)(ni * 16 + lr) * T_LEN);
      oacc[ni] = mfma16(pa, vf, oacc[ni]);
    }
  }

#pragma unroll
  for (int r = 0; r < 4; ++r) {
    const int q_idx = qbase + lg * 4 + r;
    const float inv = 1.0f / s_[r];
    const size_t rowbase = ((size_t)q_idx * BATCH + b) * DMODEL + h * DHEAD;
#pragma unroll
    for (int ni = 0; ni < 4; ++ni)
      Aout[rowbase + ni * 16 + lr] = f2bf(oacc[ni][r] * inv);
  }
}

// ---------------- launch ----------------
extern "C" void kernel_launch(void* const* d_in, const int* in_sizes, int n_in,
                              void* d_out, int out_size, void* d_ws, size_t ws_size,
                              hipStream_t stream) {
  const float* x  = (const float*)d_in[0];
  const float* Wk = (const float*)d_in[1];
  const float* Wv = (const float*)d_in[2];
  const float* Wq = (const float*)d_in[3];
  const float* Wo = (const float*)d_in[4];
  // d_in[5] = mask (causal, known structurally)

  u16* ws  = (u16*)d_ws;
  u16* xb  = ws;                       // 4M
  u16* Wkb = xb  + 4194304;            // 1M
  u16* Wvb = Wkb + 1048576;            // 1M
  u16* Wqb = Wvb + 1048576;            // 1M
  u16* Wob = Wqb + 1048576;            // 1M
  u16* Qh  = Wob + 1048576;            // 4M
  u16* Kh  = Qh  + 4194304;            // 4M
  u16* Vt  = Kh  + 4194304;            // 4M
  u16* Aout= Vt  + 4194304;            // 4M   total 24M u16 = 48MB

  cast_all<<<8192, 256, 0, stream>>>(x, Wk, Wv, Wq, Wo, ws);

  // fused QKV projections: z=0 Q, z=1 K, z=2 V(^T)
  gemm_bt<<<dim3(NDIM / 128, MROWS / 128, 3), 256, 0, stream>>>(
      xb, Wqb, Wkb, Wvb, (void*)Qh, (void*)Kh, (void*)Vt, 0);

  attn_fwd<<<dim3(T_LEN / 64, BATCH * NHEAD), 256, 0, stream>>>(Qh, Kh, Vt, Aout);

  // output projection -> f32 d_out
  gemm_bt<<<dim3(NDIM / 128, MROWS / 128, 1), 256, 0, stream>>>(
      Aout, Wob, nullptr, nullptr, d_out, nullptr, nullptr, 2);
}

// Round 2
// 204.904 us; speedup vs baseline: 1.6780x; 1.6780x over previous
//
#include <hip/hip_runtime.h>

// ---------------- problem constants ----------------
#define T_LEN   2048
#define BATCH   2
#define DMODEL  1024
#define NHEAD   16
#define DHEAD   64
#define MROWS   4096          // T*B
#define KDIM    1024
#define NDIM    1024
#define ATT_SC2 (0.125f * 1.44269504088896f)   // SCALE * log2(e), folded into Wq

typedef unsigned short u16;
typedef unsigned int   u32;
typedef u16   u16x8 __attribute__((ext_vector_type(8)));
typedef u16   u16x4 __attribute__((ext_vector_type(4)));
typedef __bf16 bf16x8 __attribute__((ext_vector_type(8)));
typedef float f32x4 __attribute__((ext_vector_type(4)));

__device__ __forceinline__ u16 f2bf(float f) {
  u32 u = __builtin_bit_cast(u32, f);
  u += 0x7fffu + ((u >> 16) & 1u);           // round-to-nearest-even
  return (u16)(u >> 16);
}

__device__ __forceinline__ f32x4 mfma16(u16x8 a, u16x8 b, f32x4 c) {
  return __builtin_amdgcn_mfma_f32_16x16x32_bf16(
      __builtin_bit_cast(bf16x8, a), __builtin_bit_cast(bf16x8, b), c, 0, 0, 0);
}

__device__ __forceinline__ void gload16(const u16* g, u16* l) {
  // async global->LDS, 16B per lane; LDS dest = wave-uniform base + lane*16
  __builtin_amdgcn_global_load_lds((const __attribute__((address_space(1))) void*)g,
                                   (__attribute__((address_space(3))) void*)l,
                                   16, 0, 0);
}

// ---------------- cast f32 -> bf16 (Wq pre-scaled by SCALE*log2e) ----------------
// ws layout (u16 elems): [xb 4M][Wkb 1M][Wvb 1M][Wqb 1M][Wob 1M][Qh 4M][Kh 4M][Vt 4M][Aout 4M]
#define XN 4194304u
__global__ __launch_bounds__(256) void cast_all(
    const float* __restrict__ x,  const float* __restrict__ wk,
    const float* __restrict__ wv, const float* __restrict__ wq,
    const float* __restrict__ wo, u16* __restrict__ dst) {
  size_t i = ((size_t)blockIdx.x * 256 + threadIdx.x) * 4;
  const float* src; size_t off; float sc = 1.0f;
  if (i < XN) { src = x; off = i; }
  else {
    size_t t = i - XN;
    int wi = (int)(t >> 20);
    off = t & 1048575u;
    src = (wi == 0) ? wk : (wi == 1) ? wv : (wi == 2) ? wq : wo;
    if (wi == 2) sc = ATT_SC2;               // fold softmax scale into Wq
  }
  float4 v = *reinterpret_cast<const float4*>(src + off);
  u16x4 o;
  o.s0 = f2bf(v.x * sc); o.s1 = f2bf(v.y * sc); o.s2 = f2bf(v.z * sc); o.s3 = f2bf(v.w * sc);
  *reinterpret_cast<u16x4*>(dst + i) = o;
}

// ---------------- bf16 GEMM: C[M,N] = A[M,K] * W[N,K]^T ----------------
__global__ __launch_bounds__(256) void gemm_bt(
    const u16* __restrict__ A,
    const u16* __restrict__ W0, const u16* __restrict__ W1, const u16* __restrict__ W2,
    void* dst0, void* dst1, void* dst2, int epi) {
  __shared__ __align__(16) u16 As[128 * 64];
  __shared__ __align__(16) u16 Bs[128 * 64];

  const int tid = threadIdx.x;
  const int l  = tid & 63, w = tid >> 6;
  const int lr = l & 15,  lg = l >> 4;
  const int wm = w >> 1,  wn = w & 1;
  const int z  = blockIdx.z;
  const u16* W = (z == 0) ? W0 : (z == 1) ? W1 : W2;
  void* dst    = (z == 0) ? dst0 : (z == 1) ? dst1 : dst2;
  const int m0 = blockIdx.y * 128;
  const int n0 = blockIdx.x * 128;

  f32x4 acc[4][4];
#pragma unroll
  for (int i = 0; i < 4; ++i)
#pragma unroll
    for (int j = 0; j < 4; ++j) acc[i][j] = (f32x4)(0.0f);

  for (int k0 = 0; k0 < KDIM; k0 += 64) {
#pragma unroll
    for (int i = 0; i < 4; ++i) {
      int p  = i * 256 + tid;
      int r  = p >> 3, cph = p & 7;
      int cl = cph ^ (r & 7);
      u16* ldsA = As + (size_t)(i * 256 + w * 64) * 8;   // wave-uniform base
      u16* ldsB = Bs + (size_t)(i * 256 + w * 64) * 8;
      gload16(A + (size_t)(m0 + r) * KDIM + k0 + cl * 8, ldsA);
      gload16(W + (size_t)(n0 + r) * KDIM + k0 + cl * 8, ldsB);
    }
    __syncthreads();

#pragma unroll
    for (int ks = 0; ks < 2; ++ks) {
      u16x8 af[4], bf_[4];
      const int cr = ks * 4 + lg;
#pragma unroll
      for (int mi = 0; mi < 4; ++mi) {
        int rr = wm * 64 + mi * 16 + lr;
        af[mi] = *reinterpret_cast<const u16x8*>(As + rr * 64 + ((cr ^ (rr & 7)) * 8));
      }
#pragma unroll
      for (int ni = 0; ni < 4; ++ni) {
        int rr = wn * 64 + ni * 16 + lr;
        bf_[ni] = *reinterpret_cast<const u16x8*>(Bs + rr * 64 + ((cr ^ (rr & 7)) * 8));
      }
#pragma unroll
      for (int mi = 0; mi < 4; ++mi)
#pragma unroll
        for (int ni = 0; ni < 4; ++ni)
          acc[mi][ni] = mfma16(af[mi], bf_[ni], acc[mi][ni]);
    }
    __syncthreads();
  }

  const int mode = (epi == 2) ? 2 : ((z == 2) ? 1 : 0);
#pragma unroll
  for (int mi = 0; mi < 4; ++mi)
#pragma unroll
    for (int ni = 0; ni < 4; ++ni)
#pragma unroll
      for (int r = 0; r < 4; ++r) {
        int row = m0 + wm * 64 + mi * 16 + lg * 4 + r;
        int col = n0 + wn * 64 + ni * 16 + lr;
        float v = acc[mi][ni][r];
        if (mode == 2) {
          ((float*)dst)[(size_t)row * NDIM + col] = v;
        } else {
          int t  = row >> 1, bb = row & 1;
          int dp = col >> 4, hh = col & 15;
          u16* d = (u16*)dst;
          if (mode == 0)
            d[((size_t)(bb * NHEAD + hh) * T_LEN + t) * DHEAD + dp] = f2bf(v);
          else
            d[((size_t)(bb * NHEAD + hh) * DHEAD + dp) * T_LEN + t] = f2bf(v);
        }
      }
}

// ---------------- causal flash attention v2 ----------------
// Swapped QK^T (lane owns one q-row), LDS-staged K/V double-buffered via
// global_load_lds + XOR swizzle, defer-max online softmax, kv-step 64.
// grid (32 qb [reversed: heavy first], 32 bh). 4 waves x 16 q-rows.
__global__ __launch_bounds__(256) void attn_fwd(
    const u16* __restrict__ Qh, const u16* __restrict__ Kh,
    const u16* __restrict__ Vt, u16* __restrict__ Aout) {
  __shared__ __align__(16) u16 Ks[2][4096];   // [64 kv][64 d], 8 chunks/row XOR-swz
  __shared__ __align__(16) u16 Vs[2][4096];   // [64 d][64 kv], 8 chunks/row XOR-swz
  __shared__ __align__(16) u16 Pl[4][16 * 72];// per-wave P tile, stride 72 (144B, 16B-aligned)

  const int tid = threadIdx.x;
  const int l = tid & 63, w = tid >> 6;
  const int lr = l & 15, lg = l >> 4;
  const int qb = (int)gridDim.x - 1 - (int)blockIdx.x;   // heavy blocks first
  const int bh = blockIdx.y;
  const int b = bh >> 4, h = bh & 15;
  const int qbase = qb * 64 + w * 16;
  const int qrow = qbase + lr;                 // this lane's softmax row

  const u16* kg = Kh + (size_t)bh * T_LEN * DHEAD;
  const u16* vg = Vt + (size_t)bh * DHEAD * T_LEN;

  // Q fragments hoisted to registers (B-frag: row = q = lr, k = d = lg*8+j)
  const u16* qptr = Qh + ((size_t)bh * T_LEN + qrow) * DHEAD + lg * 8;
  const u16x8 qf0 = *reinterpret_cast<const u16x8*>(qptr);
  const u16x8 qf1 = *reinterpret_cast<const u16x8*>(qptr + 32);

  f32x4 oacc[4];
#pragma unroll
  for (int i = 0; i < 4; ++i) oacc[i] = (f32x4)(0.0f);
  float m_ = -1e30f, s_ = 0.0f;

  const int nt = qb + 1;

  auto stage = [&](int buf, int kv0) {
#pragma unroll
    for (int j = 0; j < 2; ++j) {
      const int base = (j * 4 + w) * 64;       // chunk base (wave-uniform)
      const int r = (base + l) >> 3;           // tile row this lane loads
      const int c = l & 7;                     // physical chunk within row
      const int cs = ((c ^ (r & 7)) << 3);     // pre-swizzled source col (u16)
      gload16(kg + (size_t)(kv0 + r) * DHEAD + cs, &Ks[buf][(size_t)base * 8]);
      gload16(vg + (size_t)r * T_LEN + kv0 + cs, &Vs[buf][(size_t)base * 8]);
    }
  };

  stage(0, 0);
  __syncthreads();

  int cur = 0;
  for (int t = 0; t < nt; ++t) {
    const int kv0 = t * 64;
    if (t + 1 < nt) stage(cur ^ 1, kv0 + 64);  // prefetch next tile (hides HBM)

    // ---- QK^T swapped: D[kv16][q16]; lane holds P[kv=tt*16+lg*4+r][q=lr]
    float p[4][4];
#pragma unroll
    for (int tt = 0; tt < 4; ++tt) {
      const int row = tt * 16 + lr;            // A-frag row = kv within tile
      const u16x8 kf0 = *reinterpret_cast<const u16x8*>(
          &Ks[cur][row * 64 + ((lg ^ (row & 7)) << 3)]);
      const u16x8 kf1 = *reinterpret_cast<const u16x8*>(
          &Ks[cur][row * 64 + (((4 + lg) ^ (row & 7)) << 3)]);
      f32x4 sacc = (f32x4)(0.0f);
      sacc = mfma16(kf0, qf0, sacc);
      sacc = mfma16(kf1, qf1, sacc);
#pragma unroll
      for (int r = 0; r < 4; ++r) {
        const int kv = kv0 + tt * 16 + lg * 4 + r;
        p[tt][r] = (kv <= qrow) ? sacc[r] : -1e30f;
      }
    }

    // ---- row max: 16 in-lane + 2 shuffles (lanes lr,lr+16,lr+32,lr+48 share a row)
    float mx = p[0][0];
#pragma unroll
    for (int tt = 0; tt < 4; ++tt)
#pragma unroll
      for (int r = 0; r < 4; ++r) mx = fmaxf(mx, p[tt][r]);
    mx = fmaxf(mx, __shfl_xor(mx, 16, 64));
    mx = fmaxf(mx, __shfl_xor(mx, 32, 64));

    // ---- defer-max: rescale only when max grew by >8 (log2 domain)
    const bool need = mx > m_ + 8.0f;
    if (__any(need)) {
      const float mnew = fmaxf(m_, mx);
      const float al = __builtin_amdgcn_exp2f(m_ - mnew);
      m_ = mnew;
      s_ *= al;
#pragma unroll
      for (int r = 0; r < 4; ++r) {
        const float ab = __shfl(al, lg * 4 + r, 64);   // al for O-row q=lg*4+r
        oacc[0][r] *= ab; oacc[1][r] *= ab; oacc[2][r] *= ab; oacc[3][r] *= ab;
      }
    }

    // ---- P = exp2(S - m), row sum (in-lane + 2 shuffles)
    float sum = 0.0f;
#pragma unroll
    for (int tt = 0; tt < 4; ++tt)
#pragma unroll
      for (int r = 0; r < 4; ++r) {
        const float e = __builtin_amdgcn_exp2f(p[tt][r] - m_);
        p[tt][r] = e;
        sum += e;
      }
    sum += __shfl_xor(sum, 16, 64);
    sum += __shfl_xor(sum, 32, 64);
    s_ += sum;

    // ---- P -> LDS bf16 (wave-private; becomes PV A-fragment)
#pragma unroll
    for (int tt = 0; tt < 4; ++tt) {
      u16x4 pk;
      pk.s0 = f2bf(p[tt][0]); pk.s1 = f2bf(p[tt][1]);
      pk.s2 = f2bf(p[tt][2]); pk.s3 = f2bf(p[tt][3]);
      *reinterpret_cast<u16x4*>(&Pl[w][lr * 72 + tt * 16 + lg * 4]) = pk;
    }

    // ---- PV: O[q16][d64] += P[q16][kv64] x V^T[d][kv]
#pragma unroll
    for (int kh = 0; kh < 2; ++kh) {
      const u16x8 pa = *reinterpret_cast<const u16x8*>(
          &Pl[w][lr * 72 + kh * 32 + lg * 8]);
#pragma unroll
      for (int ni = 0; ni < 4; ++ni) {
        const int dr = ni * 16 + lr;           // B-frag row = d
        const u16x8 vf = *reinterpret_cast<const u16x8*>(
            &Vs[cur][dr * 64 + (((kh * 4 + lg) ^ (dr & 7)) << 3)]);
        oacc[ni] = mfma16(pa, vf, oacc[ni]);
      }
    }

    __syncthreads();   // drains vmcnt (next tile staged) + all waves done with cur
    cur ^= 1;
  }

  // ---- normalize + store: oacc[ni][r] = O[q=lg*4+r][d=ni*16+lr]
  const float invs = 1.0f / s_;
#pragma unroll
  for (int r = 0; r < 4; ++r) {
    const float inv = __shfl(invs, lg * 4 + r, 64);
    const int q = qbase + lg * 4 + r;
    const size_t rowbase = ((size_t)q * BATCH + b) * DMODEL + h * DHEAD;
#pragma unroll
    for (int ni = 0; ni < 4; ++ni)
      Aout[rowbase + ni * 16 + lr] = f2bf(oacc[ni][r] * inv);
  }
}

// ---------------- launch ----------------
extern "C" void kernel_launch(void* const* d_in, const int* in_sizes, int n_in,
                              void* d_out, int out_size, void* d_ws, size_t ws_size,
                              hipStream_t stream) {
  const float* x  = (const float*)d_in[0];
  const float* Wk = (const float*)d_in[1];
  const float* Wv = (const float*)d_in[2];
  const float* Wq = (const float*)d_in[3];
  const float* Wo = (const float*)d_in[4];
  // d_in[5] = mask (causal, known structurally)

  u16* ws  = (u16*)d_ws;
  u16* xb  = ws;                       // 4M
  u16* Wkb = xb  + 4194304;            // 1M
  u16* Wvb = Wkb + 1048576;            // 1M
  u16* Wqb = Wvb + 1048576;            // 1M (pre-scaled)
  u16* Wob = Wqb + 1048576;            // 1M
  u16* Qh  = Wob + 1048576;            // 4M
  u16* Kh  = Qh  + 4194304;            // 4M
  u16* Vt  = Kh  + 4194304;            // 4M
  u16* Aout= Vt  + 4194304;            // 4M   total 24M u16 = 48MB

  cast_all<<<8192, 256, 0, stream>>>(x, Wk, Wv, Wq, Wo, ws);

  // fused QKV projections: z=0 Q, z=1 K, z=2 V(^T)
  gemm_bt<<<dim3(NDIM / 128, MROWS / 128, 3), 256, 0, stream>>>(
      xb, Wqb, Wkb, Wvb, (void*)Qh, (void*)Kh, (void*)Vt, 0);

  attn_fwd<<<dim3(T_LEN / 64, BATCH * NHEAD), 256, 0, stream>>>(Qh, Kh, Vt, Aout);

  // output projection -> f32 d_out
  gemm_bt<<<dim3(NDIM / 128, MROWS / 128, 1), 256, 0, stream>>>(
      Aout, Wob, nullptr, nullptr, d_out, nullptr, nullptr, 2);
}

// Round 3
// 137.703 us; speedup vs baseline: 2.4968x; 1.4880x over previous
//
#include <hip/hip_runtime.h>

// ---------------- problem constants ----------------
#define T_LEN   2048
#define BATCH   2
#define DMODEL  1024
#define NHEAD   16
#define DHEAD   64
#define MROWS   4096          // T*B
#define KDIM    1024
#define NDIM    1024
#define ATT_SC2 (0.125f * 1.44269504088896f)   // SCALE * log2(e), folded into Wq

typedef unsigned short u16;
typedef unsigned int   u32;
typedef u16   u16x8 __attribute__((ext_vector_type(8)));
typedef u16   u16x4 __attribute__((ext_vector_type(4)));
typedef __bf16 bf16x8 __attribute__((ext_vector_type(8)));
typedef float f32x4 __attribute__((ext_vector_type(4)));

__device__ __forceinline__ u16 f2bf(float f) {
  u32 u = __builtin_bit_cast(u32, f);
  u += 0x7fffu + ((u >> 16) & 1u);           // round-to-nearest-even
  return (u16)(u >> 16);
}

__device__ __forceinline__ f32x4 mfma16(u16x8 a, u16x8 b, f32x4 c) {
  return __builtin_amdgcn_mfma_f32_16x16x32_bf16(
      __builtin_bit_cast(bf16x8, a), __builtin_bit_cast(bf16x8, b), c, 0, 0, 0);
}

__device__ __forceinline__ void gload16(const u16* g, u16* l) {
  // async global->LDS, 16B per lane; LDS dest = wave-uniform base + lane*16
  __builtin_amdgcn_global_load_lds((const __attribute__((address_space(1))) void*)g,
                                   (__attribute__((address_space(3))) void*)l,
                                   16, 0, 0);
}

// ---------------- cast f32 -> bf16 with layout fixes ----------------
// ws layout (u16): [xbm 4M][Wkb 1M][Wvb 1M][Wqb 1M][Wob 1M][Qh 4M][Kh 4M][Vt 4M][Aout 4M]
// xbm   : x[t][b][d]  ->  [b*2048+t][d]        (batch-major rows)
// Wk/Wv/Wq : row u=dp*16+h -> row u'=h*64+dp   (head-outer columns after GEMM)
// Wq additionally scaled by SCALE*log2(e); Wo unpermuted.
#define XN 4194304u
__global__ __launch_bounds__(256) void cast_all(
    const float* __restrict__ x,  const float* __restrict__ wk,
    const float* __restrict__ wv, const float* __restrict__ wq,
    const float* __restrict__ wo, u16* __restrict__ ws) {
  size_t i = ((size_t)blockIdx.x * 256 + threadIdx.x) * 4;
  const float* src; size_t soff, doff; float sc = 1.0f;
  if (i < XN) {
    int m = (int)(i >> 10), d = (int)(i & 1023);
    int t = m >> 1, b = m & 1;
    src = x; soff = i;
    doff = ((size_t)(b * 2048 + t) << 10) + d;
  } else {
    size_t off = i - XN;
    int wi = (int)(off >> 20);
    off &= 1048575u;
    int u = (int)(off >> 10), c = (int)(off & 1023);
    src = (wi == 0) ? wk : (wi == 1) ? wv : (wi == 2) ? wq : wo;
    soff = off;
    if (wi == 3) {
      doff = XN + 3u * 1048576u + off;                      // Wob linear
    } else {
      int up = (u & 15) * 64 + (u >> 4);                    // head-outer perm
      doff = XN + (size_t)wi * 1048576u + ((size_t)up << 10) + c;
      if (wi == 2) sc = ATT_SC2;
    }
  }
  float4 v = *reinterpret_cast<const float4*>(src + soff);
  u16x4 o;
  o.s0 = f2bf(v.x * sc); o.s1 = f2bf(v.y * sc); o.s2 = f2bf(v.z * sc); o.s3 = f2bf(v.w * sc);
  *reinterpret_cast<u16x4*>(ws + doff) = o;
}

// ---------------- bf16 GEMM: C = A * W^T, 128x128 tile, BK=64 ----------------
// epi=0 (QKV launch): z=0: A=X(xbm),W=W0(Wq)->d0 Qh ; z=1: W1(Wk)->d1 Kh
//                     z=2: SWAPPED A=W2(Wv), W=X -> d2 = V^T directly
// epi=2 (O launch)  : A=X(Aout), W=W0(Wo) -> d0 f32, rows un-permuted to [t][b]
__global__ __launch_bounds__(256) void gemm_bt(
    const u16* __restrict__ X,
    const u16* __restrict__ W0, const u16* __restrict__ W1, const u16* __restrict__ W2,
    void* d0, void* d1, void* d2, int epi) {
  __shared__ __align__(16) u16 As[128 * 64];
  __shared__ __align__(16) u16 Bs[128 * 64];

  const int tid = threadIdx.x;
  const int l  = tid & 63, w = tid >> 6;
  const int lr = l & 15,  lg = l >> 4;
  const int wm = w >> 1,  wn = w & 1;
  const int z  = blockIdx.z;
  int bx = blockIdx.x, by = blockIdx.y;

  const u16 *A, *W; void* dst; int mode;
  if (epi == 2)      { A = X;  W = W0; dst = d0; mode = 2; }
  else if (z == 0)   { A = X;  W = W0; dst = d0; mode = 0; }
  else if (z == 1)   { A = X;  W = W1; dst = d1; mode = 0; }
  else {                                   // V swapped: M=1024, N=4096
    A = W2; W = X; dst = d2; mode = 1;
    int flat = by * 8 + bx;
    bx = flat >> 3; by = flat & 7;
  }
  const int m0 = by * 128;
  const int n0 = bx * 128;

  f32x4 acc[4][4];
#pragma unroll
  for (int i = 0; i < 4; ++i)
#pragma unroll
    for (int j = 0; j < 4; ++j) acc[i][j] = (f32x4)(0.0f);

  for (int k0 = 0; k0 < KDIM; k0 += 64) {
#pragma unroll
    for (int i = 0; i < 4; ++i) {
      int p  = i * 256 + tid;
      int r  = p >> 3, cph = p & 7;
      int cl = cph ^ (r & 7);
      u16* ldsA = As + (size_t)(i * 256 + w * 64) * 8;   // wave-uniform base
      u16* ldsB = Bs + (size_t)(i * 256 + w * 64) * 8;
      gload16(A + (size_t)(m0 + r) * KDIM + k0 + cl * 8, ldsA);
      gload16(W + (size_t)(n0 + r) * KDIM + k0 + cl * 8, ldsB);
    }
    __syncthreads();

#pragma unroll
    for (int ks = 0; ks < 2; ++ks) {
      u16x8 af[4], bf_[4];
      const int cr = ks * 4 + lg;
#pragma unroll
      for (int mi = 0; mi < 4; ++mi) {
        int rr = wm * 64 + mi * 16 + lr;
        af[mi] = *reinterpret_cast<const u16x8*>(As + rr * 64 + ((cr ^ (rr & 7)) * 8));
      }
#pragma unroll
      for (int ni = 0; ni < 4; ++ni) {
        int rr = wn * 64 + ni * 16 + lr;
        bf_[ni] = *reinterpret_cast<const u16x8*>(Bs + rr * 64 + ((cr ^ (rr & 7)) * 8));
      }
#pragma unroll
      for (int mi = 0; mi < 4; ++mi)
#pragma unroll
        for (int ni = 0; ni < 4; ++ni)
          acc[mi][ni] = mfma16(af[mi], bf_[ni], acc[mi][ni]);
    }
    __syncthreads();
  }

#pragma unroll
  for (int mi = 0; mi < 4; ++mi)
#pragma unroll
    for (int ni = 0; ni < 4; ++ni)
#pragma unroll
      for (int r = 0; r < 4; ++r) {
        int row = m0 + wm * 64 + mi * 16 + lg * 4 + r;
        int col = n0 + wn * 64 + ni * 16 + lr;
        float v = acc[mi][ni][r];
        if (mode == 2) {
          // row = b*2048+t -> out[(t*2+b)][col], coalesced f32
          int t = row & 2047, bb = row >> 11;
          ((float*)dst)[((size_t)(t * 2 + bb) << 10) + col] = v;
        } else if (mode == 0) {
          // Q/K: row=b*2048+t, col=h*64+dp -> [bh][t][dp], 32B runs
          int bb = row >> 11, t = row & 2047;
          int hh = col >> 6, dp = col & 63;
          ((u16*)dst)[(((size_t)(bb * NHEAD + hh) << 11) + t) * 64 + dp] = f2bf(v);
        } else {
          // V^T: row=h*64+dp, col=b*2048+t -> [bh][dp][t], 32B runs
          int hh = row >> 6, dp = row & 63;
          int bb = col >> 11, t = col & 2047;
          ((u16*)dst)[((((size_t)(bb * NHEAD + hh)) * 64 + dp) << 11) + t] = f2bf(v);
        }
      }
}

// ---------------- causal flash attention v3 ----------------
// Paired-uniform schedule: block bx handles qb = 31-bx then qb = bx (33 tiles
// total each) -> zero tail. grid (16, 32bh), 4 waves x 16 q-rows, kv-step 64.
// Swapped QK^T, LDS K/V double-buffer via global_load_lds + XOR swizzle,
// defer-max, diagonal-only masking.
__global__ __launch_bounds__(256) void attn_fwd(
    const u16* __restrict__ Qh, const u16* __restrict__ Kh,
    const u16* __restrict__ Vt, u16* __restrict__ Aout) {
  __shared__ __align__(16) u16 Ks[2][4096];   // [64 kv][64 d], XOR-swz chunks
  __shared__ __align__(16) u16 Vs[2][4096];   // [64 d][64 kv], XOR-swz chunks
  __shared__ __align__(16) u16 Pl[4][16 * 72];

  const int tid = threadIdx.x;
  const int l = tid & 63, w = tid >> 6;
  const int lr = l & 15, lg = l >> 4;
  const int bxx = blockIdx.x, bh = blockIdx.y;
  const int b = bh >> 4, h = bh & 15;

  const u16* kg = Kh + ((size_t)bh << 11) * DHEAD;
  const u16* vg = Vt + ((size_t)bh << 11) * DHEAD;

  auto stage = [&](int buf, int kv0) {
#pragma unroll
    for (int j = 0; j < 2; ++j) {
      const int base = (j * 4 + w) * 64;       // chunk base (wave-uniform)
      const int r = (base + l) >> 3;           // tile row this lane loads
      const int c = l & 7;                     // physical chunk within row
      const int cs = ((c ^ (r & 7)) << 3);     // pre-swizzled source col (u16)
      gload16(kg + (size_t)(kv0 + r) * DHEAD + cs, &Ks[buf][(size_t)base * 8]);
      gload16(vg + ((size_t)r << 11) + kv0 + cs, &Vs[buf][(size_t)base * 8]);
    }
  };

  for (int ph = 0; ph < 2; ++ph) {
    const int qb = ph ? bxx : 31 - bxx;
    const int qbase = qb * 64 + w * 16;
    const int qrow = qbase + lr;

    const u16* qptr = Qh + (((size_t)bh << 11) + qrow) * DHEAD + lg * 8;
    const u16x8 qf0 = *reinterpret_cast<const u16x8*>(qptr);
    const u16x8 qf1 = *reinterpret_cast<const u16x8*>(qptr + 32);

    f32x4 oacc[4];
#pragma unroll
    for (int i = 0; i < 4; ++i) oacc[i] = (f32x4)(0.0f);
    float m_ = -1e30f, s_ = 0.0f;

    const int nt = qb + 1;
    stage(0, 0);
    __syncthreads();

    int cur = 0;
    for (int t = 0; t < nt; ++t) {
      const int kv0 = t * 64;
      if (t + 1 < nt) stage(cur ^ 1, kv0 + 64);

      // ---- QK^T swapped: lane holds P[kv=tt*16+lg*4+r][q=lr]
      float p[4][4];
#pragma unroll
      for (int tt = 0; tt < 4; ++tt) {
        const int row = tt * 16 + lr;
        const u16x8 kf0 = *reinterpret_cast<const u16x8*>(
            &Ks[cur][row * 64 + ((lg ^ (row & 7)) << 3)]);
        const u16x8 kf1 = *reinterpret_cast<const u16x8*>(
            &Ks[cur][row * 64 + (((4 + lg) ^ (row & 7)) << 3)]);
        f32x4 sacc = (f32x4)(0.0f);
        sacc = mfma16(kf0, qf0, sacc);
        sacc = mfma16(kf1, qf1, sacc);
#pragma unroll
        for (int r = 0; r < 4; ++r) p[tt][r] = sacc[r];
      }
      if (t == nt - 1) {                       // diagonal tile only: causal mask
#pragma unroll
        for (int tt = 0; tt < 4; ++tt)
#pragma unroll
          for (int r = 0; r < 4; ++r) {
            const int kv = kv0 + tt * 16 + lg * 4 + r;
            if (kv > qrow) p[tt][r] = -1e30f;
          }
      }

      // ---- row max: 15 in-lane + 2 shuffles
      float mx = p[0][0];
#pragma unroll
      for (int tt = 0; tt < 4; ++tt)
#pragma unroll
        for (int r = 0; r < 4; ++r) mx = fmaxf(mx, p[tt][r]);
      mx = fmaxf(mx, __shfl_xor(mx, 16, 64));
      mx = fmaxf(mx, __shfl_xor(mx, 32, 64));

      // ---- defer-max rescale
      const bool need = mx > m_ + 8.0f;
      if (__any(need)) {
        const float mnew = fmaxf(m_, mx);
        const float al = __builtin_amdgcn_exp2f(m_ - mnew);
        m_ = mnew;
        s_ *= al;
#pragma unroll
        for (int r = 0; r < 4; ++r) {
          const float ab = __shfl(al, lg * 4 + r, 64);
          oacc[0][r] *= ab; oacc[1][r] *= ab; oacc[2][r] *= ab; oacc[3][r] *= ab;
        }
      }

      // ---- P = exp2(S - m), row sum
      float sum = 0.0f;
#pragma unroll
      for (int tt = 0; tt < 4; ++tt)
#pragma unroll
        for (int r = 0; r < 4; ++r) {
          const float e = __builtin_amdgcn_exp2f(p[tt][r] - m_);
          p[tt][r] = e;
          sum += e;
        }
      sum += __shfl_xor(sum, 16, 64);
      sum += __shfl_xor(sum, 32, 64);
      s_ += sum;

      // ---- P -> LDS bf16 (wave-private) -> PV A-fragment
#pragma unroll
      for (int tt = 0; tt < 4; ++tt) {
        u16x4 pk;
        pk.s0 = f2bf(p[tt][0]); pk.s1 = f2bf(p[tt][1]);
        pk.s2 = f2bf(p[tt][2]); pk.s3 = f2bf(p[tt][3]);
        *reinterpret_cast<u16x4*>(&Pl[w][lr * 72 + tt * 16 + lg * 4]) = pk;
      }

      // ---- PV: O[q16][d64] += P[q16][kv64] x V^T[d][kv]
#pragma unroll
      for (int kh = 0; kh < 2; ++kh) {
        const u16x8 pa = *reinterpret_cast<const u16x8*>(
            &Pl[w][lr * 72 + kh * 32 + lg * 8]);
#pragma unroll
        for (int ni = 0; ni < 4; ++ni) {
          const int dr = ni * 16 + lr;
          const u16x8 vf = *reinterpret_cast<const u16x8*>(
              &Vs[cur][dr * 64 + (((kh * 4 + lg) ^ (dr & 7)) << 3)]);
          oacc[ni] = mfma16(pa, vf, oacc[ni]);
        }
      }

      __syncthreads();   // next tile staged + all waves done with cur
      cur ^= 1;
    }

    // ---- normalize + store: Aout[b*2048+q][h*64+dp]
    const float invs = 1.0f / s_;
#pragma unroll
    for (int r = 0; r < 4; ++r) {
      const float inv = __shfl(invs, lg * 4 + r, 64);
      const int q = qbase + lg * 4 + r;
      const size_t rowbase = (((size_t)(b * 2048 + q)) << 10) + h * DHEAD;
#pragma unroll
      for (int ni = 0; ni < 4; ++ni)
        Aout[rowbase + ni * 16 + lr] = f2bf(oacc[ni][r] * inv);
    }
  }
}

// ---------------- launch ----------------
extern "C" void kernel_launch(void* const* d_in, const int* in_sizes, int n_in,
                              void* d_out, int out_size, void* d_ws, size_t ws_size,
                              hipStream_t stream) {
  const float* x  = (const float*)d_in[0];
  const float* Wk = (const float*)d_in[1];
  const float* Wv = (const float*)d_in[2];
  const float* Wq = (const float*)d_in[3];
  const float* Wo = (const float*)d_in[4];
  // d_in[5] = mask (causal, known structurally)

  u16* ws  = (u16*)d_ws;
  u16* xbm = ws;                       // 4M  [b*2048+t][d]
  u16* Wkb = xbm + 4194304;            // 1M  (head-outer rows)
  u16* Wvb = Wkb + 1048576;            // 1M  (head-outer rows)
  u16* Wqb = Wvb + 1048576;            // 1M  (head-outer rows, pre-scaled)
  u16* Wob = Wqb + 1048576;            // 1M  (unpermuted)
  u16* Qh  = Wob + 1048576;            // 4M  [bh][t][64]
  u16* Kh  = Qh  + 4194304;            // 4M  [bh][t][64]
  u16* Vt  = Kh  + 4194304;            // 4M  [bh][64][t]
  u16* Aout= Vt  + 4194304;            // 4M  [b*2048+t][h*64+dp]

  cast_all<<<8192, 256, 0, stream>>>(x, Wk, Wv, Wq, Wo, ws);

  // QKV: z=0 Q, z=1 K, z=2 V (swapped -> V^T directly)
  gemm_bt<<<dim3(8, 32, 3), 256, 0, stream>>>(
      xbm, Wqb, Wkb, Wvb, (void*)Qh, (void*)Kh, (void*)Vt, 0);

  attn_fwd<<<dim3(16, BATCH * NHEAD), 256, 0, stream>>>(Qh, Kh, Vt, Aout);

  // output projection -> f32 d_out (rows un-permuted to [t][b])
  gemm_bt<<<dim3(8, 32, 1), 256, 0, stream>>>(
      Aout, Wob, nullptr, nullptr, d_out, nullptr, nullptr, 2);
}

// Round 4
// 125.728 us; speedup vs baseline: 2.7347x; 1.0952x over previous
//
#include <hip/hip_runtime.h>

// ---------------- problem constants ----------------
#define T_LEN   2048
#define BATCH   2
#define DMODEL  1024
#define NHEAD   16
#define DHEAD   64
#define MROWS   4096          // T*B
#define KDIM    1024
#define NDIM    1024
#define ATT_SC2 (0.125f * 1.44269504088896f)   // SCALE * log2(e), folded into Wq

typedef unsigned short u16;
typedef unsigned int   u32;
typedef u16   u16x8 __attribute__((ext_vector_type(8)));
typedef u16   u16x4 __attribute__((ext_vector_type(4)));
typedef __bf16 bf16x8 __attribute__((ext_vector_type(8)));
typedef float f32x4 __attribute__((ext_vector_type(4)));

__device__ __forceinline__ u16 f2bf(float f) {
  u32 u = __builtin_bit_cast(u32, f);
  u += 0x7fffu + ((u >> 16) & 1u);           // round-to-nearest-even
  return (u16)(u >> 16);
}

__device__ __forceinline__ u16 bfc(float f) {  // compiler cvt (RNE, packs to cvt_pk)
  return __builtin_bit_cast(u16, (__bf16)f);
}

__device__ __forceinline__ f32x4 mfma16(u16x8 a, u16x8 b, f32x4 c) {
  return __builtin_amdgcn_mfma_f32_16x16x32_bf16(
      __builtin_bit_cast(bf16x8, a), __builtin_bit_cast(bf16x8, b), c, 0, 0, 0);
}

__device__ __forceinline__ void gload16(const u16* g, u16* l) {
  // async global->LDS, 16B per lane; LDS dest = wave-uniform base + lane*16
  __builtin_amdgcn_global_load_lds((const __attribute__((address_space(1))) void*)g,
                                   (__attribute__((address_space(3))) void*)l,
                                   16, 0, 0);
}

// ---------------- cast f32 -> bf16 with layout fixes ----------------
// ws layout (u16): [xbm 4M][Wkb 1M][Wvb 1M][Wqb 1M][Wob 1M][Qh 4M][Kh 4M][Vt 4M][Aout 4M]
#define XN 4194304u
__global__ __launch_bounds__(256) void cast_all(
    const float* __restrict__ x,  const float* __restrict__ wk,
    const float* __restrict__ wv, const float* __restrict__ wq,
    const float* __restrict__ wo, u16* __restrict__ ws) {
  size_t i = ((size_t)blockIdx.x * 256 + threadIdx.x) * 4;
  const float* src; size_t soff, doff; float sc = 1.0f;
  if (i < XN) {
    int m = (int)(i >> 10), d = (int)(i & 1023);
    int t = m >> 1, b = m & 1;
    src = x; soff = i;
    doff = ((size_t)(b * 2048 + t) << 10) + d;
  } else {
    size_t off = i - XN;
    int wi = (int)(off >> 20);
    off &= 1048575u;
    int u = (int)(off >> 10), c = (int)(off & 1023);
    src = (wi == 0) ? wk : (wi == 1) ? wv : (wi == 2) ? wq : wo;
    soff = off;
    if (wi == 3) {
      doff = XN + 3u * 1048576u + off;                      // Wob linear
    } else {
      int up = (u & 15) * 64 + (u >> 4);                    // head-outer perm
      doff = XN + (size_t)wi * 1048576u + ((size_t)up << 10) + c;
      if (wi == 2) sc = ATT_SC2;
    }
  }
  float4 v = *reinterpret_cast<const float4*>(src + soff);
  u16x4 o;
  o.s0 = f2bf(v.x * sc); o.s1 = f2bf(v.y * sc); o.s2 = f2bf(v.z * sc); o.s3 = f2bf(v.w * sc);
  *reinterpret_cast<u16x4*>(ws + doff) = o;
}

// ---------------- bf16 GEMM: C = A * W^T, 128x128 tile, BK=64 ----------------
__global__ __launch_bounds__(256) void gemm_bt(
    const u16* __restrict__ X,
    const u16* __restrict__ W0, const u16* __restrict__ W1, const u16* __restrict__ W2,
    void* d0, void* d1, void* d2, int epi) {
  __shared__ __align__(16) u16 As[128 * 64];
  __shared__ __align__(16) u16 Bs[128 * 64];

  const int tid = threadIdx.x;
  const int l  = tid & 63, w = tid >> 6;
  const int lr = l & 15,  lg = l >> 4;
  const int wm = w >> 1,  wn = w & 1;
  const int z  = blockIdx.z;
  int bx = blockIdx.x, by = blockIdx.y;

  const u16 *A, *W; void* dst; int mode;
  if (epi == 2)      { A = X;  W = W0; dst = d0; mode = 2; }
  else if (z == 0)   { A = X;  W = W0; dst = d0; mode = 0; }
  else if (z == 1)   { A = X;  W = W1; dst = d1; mode = 0; }
  else {                                   // V swapped: M=1024, N=4096
    A = W2; W = X; dst = d2; mode = 1;
    int flat = by * 8 + bx;
    bx = flat >> 3; by = flat & 7;
  }
  const int m0 = by * 128;
  const int n0 = bx * 128;

  f32x4 acc[4][4];
#pragma unroll
  for (int i = 0; i < 4; ++i)
#pragma unroll
    for (int j = 0; j < 4; ++j) acc[i][j] = (f32x4)(0.0f);

  for (int k0 = 0; k0 < KDIM; k0 += 64) {
#pragma unroll
    for (int i = 0; i < 4; ++i) {
      int p  = i * 256 + tid;
      int r  = p >> 3, cph = p & 7;
      int cl = cph ^ (r & 7);
      u16* ldsA = As + (size_t)(i * 256 + w * 64) * 8;   // wave-uniform base
      u16* ldsB = Bs + (size_t)(i * 256 + w * 64) * 8;
      gload16(A + (size_t)(m0 + r) * KDIM + k0 + cl * 8, ldsA);
      gload16(W + (size_t)(n0 + r) * KDIM + k0 + cl * 8, ldsB);
    }
    __syncthreads();

#pragma unroll
    for (int ks = 0; ks < 2; ++ks) {
      u16x8 af[4], bf_[4];
      const int cr = ks * 4 + lg;
#pragma unroll
      for (int mi = 0; mi < 4; ++mi) {
        int rr = wm * 64 + mi * 16 + lr;
        af[mi] = *reinterpret_cast<const u16x8*>(As + rr * 64 + ((cr ^ (rr & 7)) * 8));
      }
#pragma unroll
      for (int ni = 0; ni < 4; ++ni) {
        int rr = wn * 64 + ni * 16 + lr;
        bf_[ni] = *reinterpret_cast<const u16x8*>(Bs + rr * 64 + ((cr ^ (rr & 7)) * 8));
      }
#pragma unroll
      for (int mi = 0; mi < 4; ++mi)
#pragma unroll
        for (int ni = 0; ni < 4; ++ni)
          acc[mi][ni] = mfma16(af[mi], bf_[ni], acc[mi][ni]);
    }
    __syncthreads();
  }

#pragma unroll
  for (int mi = 0; mi < 4; ++mi)
#pragma unroll
    for (int ni = 0; ni < 4; ++ni)
#pragma unroll
      for (int r = 0; r < 4; ++r) {
        int row = m0 + wm * 64 + mi * 16 + lg * 4 + r;
        int col = n0 + wn * 64 + ni * 16 + lr;
        float v = acc[mi][ni][r];
        if (mode == 2) {
          int t = row & 2047, bb = row >> 11;
          ((float*)dst)[((size_t)(t * 2 + bb) << 10) + col] = v;
        } else if (mode == 0) {
          int bb = row >> 11, t = row & 2047;
          int hh = col >> 6, dp = col & 63;
          ((u16*)dst)[(((size_t)(bb * NHEAD + hh) << 11) + t) * 64 + dp] = f2bf(v);
        } else {
          int hh = row >> 6, dp = row & 63;
          int bb = col >> 11, t = col & 2047;
          ((u16*)dst)[((((size_t)(bb * NHEAD + hh)) * 64 + dp) << 11) + t] = f2bf(v);
        }
      }
}

// ---------------- causal flash attention v4 ----------------
// kv-step 128, paired-uniform qb schedule, XCD-grouped heads, swapped QK^T,
// MFMA row-sum (ones trick), XOR-swizzled P tile, defer-max.
// 1-D grid 512: blk = k*8 + (bh&7); k = (bh>>3)*16 + bx  -> 4 heads per XCD.
__global__ __launch_bounds__(256) void attn_fwd(
    const u16* __restrict__ Qh, const u16* __restrict__ Kh,
    const u16* __restrict__ Vt, u16* __restrict__ Aout) {
  __shared__ __align__(16) u16 Ks[2][8192];   // [128 kv][64 d], chunk^ (r&7)
  __shared__ __align__(16) u16 Vs[2][8192];   // [64 d][128 kv], chunk^ (r&15)
  __shared__ __align__(16) u16 Pl[4][1024];   // per-wave [16 q][64 kv], chunk^(lr&7)

  const int tid = threadIdx.x;
  const int l = tid & 63, w = tid >> 6;
  const int lr = l & 15, lg = l >> 4;
  const int blk = blockIdx.x;
  const int bxx = (blk >> 3) & 15;
  const int bh  = ((blk >> 7) << 3) + (blk & 7);
  const int b = bh >> 4, h = bh & 15;

  const u16* kg = Kh + ((size_t)bh << 17);    // [t][64]
  const u16* vg = Vt + ((size_t)bh << 17);    // [64][2048]

  const u16x8 ones = {0x3F80,0x3F80,0x3F80,0x3F80,0x3F80,0x3F80,0x3F80,0x3F80};

  auto stage = [&](int buf, int kv0) {
#pragma unroll
    for (int j = 0; j < 4; ++j) {
      const int base = (j * 4 + w) * 64;       // chunk base (wave-uniform)
      const int g = base + l;
      const int rk = g >> 3, ck = g & 7;       // K: 8 chunks/row
      gload16(kg + (size_t)(kv0 + rk) * 64 + ((ck ^ (rk & 7)) << 3),
              &Ks[buf][(size_t)base * 8]);
      const int rv = g >> 4, cv = g & 15;      // V: 16 chunks/row
      gload16(vg + ((size_t)rv << 11) + kv0 + ((cv ^ (rv & 15)) << 3),
              &Vs[buf][(size_t)base * 8]);
    }
  };

  for (int ph = 0; ph < 2; ++ph) {
    const int qb = ph ? bxx : 31 - bxx;
    const int qbase = qb * 64 + w * 16;
    const int qrow = qbase + lr;

    const u16* qptr = Qh + (((size_t)bh << 11) + qrow) * 64 + lg * 8;
    const u16x8 qf0 = *reinterpret_cast<const u16x8*>(qptr);
    const u16x8 qf1 = *reinterpret_cast<const u16x8*>(qptr + 32);

    f32x4 oacc[4];
#pragma unroll
    for (int i = 0; i < 4; ++i) oacc[i] = (f32x4)(0.0f);
    f32x4 sum4 = (f32x4)(0.0f);
    float m_ = -1e30f;

    const int npair = (qb + 2) >> 1;
    stage(0, 0);
    __syncthreads();

    int cur = 0;
    for (int t = 0; t < npair; ++t) {
      const int kv0 = t * 128;
      if (t + 1 < npair) stage(cur ^ 1, kv0 + 128);

      // ---- QK^T swapped: p[hh][tt][r] = S[kv=hh*64+tt*16+lg*4+r][q=lr]
      float p[2][4][4];
      __builtin_amdgcn_s_setprio(1);
#pragma unroll
      for (int hh = 0; hh < 2; ++hh) {
        const int i64 = 2 * t + hh;
        if (i64 <= qb) {
#pragma unroll
          for (int tt = 0; tt < 4; ++tt) {
            const int row = hh * 64 + tt * 16 + lr;
            const u16x8 kf0 = *reinterpret_cast<const u16x8*>(
                &Ks[cur][row * 64 + ((lg ^ (row & 7)) << 3)]);
            const u16x8 kf1 = *reinterpret_cast<const u16x8*>(
                &Ks[cur][row * 64 + (((4 + lg) ^ (row & 7)) << 3)]);
            f32x4 sacc = (f32x4)(0.0f);
            sacc = mfma16(kf0, qf0, sacc);
            sacc = mfma16(kf1, qf1, sacc);
#pragma unroll
            for (int r = 0; r < 4; ++r) p[hh][tt][r] = sacc[r];
          }
          if (i64 == qb) {                     // diagonal tile: causal mask
#pragma unroll
            for (int tt = 0; tt < 4; ++tt)
#pragma unroll
              for (int r = 0; r < 4; ++r) {
                const int kv = kv0 + hh * 64 + tt * 16 + lg * 4 + r;
                if (kv > qrow) p[hh][tt][r] = -1e30f;
              }
          }
        } else {                               // beyond diagonal: fully masked
#pragma unroll
          for (int tt = 0; tt < 4; ++tt)
#pragma unroll
            for (int r = 0; r < 4; ++r) p[hh][tt][r] = -1e30f;
        }
      }
      __builtin_amdgcn_s_setprio(0);

      // ---- row max: 31 in-lane + 2 shuffles
      float mx = p[0][0][0];
#pragma unroll
      for (int hh = 0; hh < 2; ++hh)
#pragma unroll
        for (int tt = 0; tt < 4; ++tt)
#pragma unroll
          for (int r = 0; r < 4; ++r) mx = fmaxf(mx, p[hh][tt][r]);
      mx = fmaxf(mx, __shfl_xor(mx, 16, 64));
      mx = fmaxf(mx, __shfl_xor(mx, 32, 64));

      // ---- defer-max rescale (rare)
      if (__any(mx > m_ + 8.0f)) {
        const float mnew = fmaxf(m_, mx);
        const float al = __builtin_amdgcn_exp2f(m_ - mnew);
        m_ = mnew;
#pragma unroll
        for (int r = 0; r < 4; ++r) {
          const float ab = __shfl(al, lg * 4 + r, 64);
          sum4[r] *= ab;
          oacc[0][r] *= ab; oacc[1][r] *= ab; oacc[2][r] *= ab; oacc[3][r] *= ab;
        }
      }

      // ---- P = exp2(S - m)
#pragma unroll
      for (int hh = 0; hh < 2; ++hh)
#pragma unroll
        for (int tt = 0; tt < 4; ++tt)
#pragma unroll
          for (int r = 0; r < 4; ++r)
            p[hh][tt][r] = __builtin_amdgcn_exp2f(p[hh][tt][r] - m_);

      // ---- per 64-kv half: pack P -> Pl, then PV + MFMA row-sum
#pragma unroll
      for (int kvh = 0; kvh < 2; ++kvh) {
#pragma unroll
        for (int tt = 0; tt < 4; ++tt) {
          u16x4 pk;
          pk.s0 = bfc(p[kvh][tt][0]); pk.s1 = bfc(p[kvh][tt][1]);
          pk.s2 = bfc(p[kvh][tt][2]); pk.s3 = bfc(p[kvh][tt][3]);
          *reinterpret_cast<u16x4*>(
              &Pl[w][lr * 64 + (((tt * 2 + (lg >> 1)) ^ (lr & 7)) << 3)
                     + ((lg & 1) << 2)]) = pk;
        }
        __builtin_amdgcn_s_setprio(1);
#pragma unroll
        for (int kh = 0; kh < 2; ++kh) {
          const u16x8 pa = *reinterpret_cast<const u16x8*>(
              &Pl[w][lr * 64 + (((kh * 4 + lg) ^ (lr & 7)) << 3)]);
          sum4 = mfma16(pa, ones, sum4);       // row-sum in O's C-layout
#pragma unroll
          for (int ni = 0; ni < 4; ++ni) {
            const int dr = ni * 16 + lr;
            const int ck = kvh * 8 + kh * 4 + lg;
            const u16x8 vf = *reinterpret_cast<const u16x8*>(
                &Vs[cur][dr * 128 + ((ck ^ (dr & 15)) << 3)]);
            oacc[ni] = mfma16(pa, vf, oacc[ni]);
          }
        }
        __builtin_amdgcn_s_setprio(0);
      }

      __syncthreads();   // next tile staged + all waves done with cur
      cur ^= 1;
    }

    // ---- normalize + store (sum4[r] already matches O rows; no shuffles)
#pragma unroll
    for (int r = 0; r < 4; ++r) {
      const float inv = 1.0f / sum4[r];
      const int q = qbase + lg * 4 + r;
      const size_t rowbase = (((size_t)(b * 2048 + q)) << 10) + h * DHEAD;
#pragma unroll
      for (int ni = 0; ni < 4; ++ni)
        Aout[rowbase + ni * 16 + lr] = bfc(oacc[ni][r] * inv);
    }
  }
}

// ---------------- launch ----------------
extern "C" void kernel_launch(void* const* d_in, const int* in_sizes, int n_in,
                              void* d_out, int out_size, void* d_ws, size_t ws_size,
                              hipStream_t stream) {
  const float* x  = (const float*)d_in[0];
  const float* Wk = (const float*)d_in[1];
  const float* Wv = (const float*)d_in[2];
  const float* Wq = (const float*)d_in[3];
  const float* Wo = (const float*)d_in[4];
  // d_in[5] = mask (causal, known structurally)

  u16* ws  = (u16*)d_ws;
  u16* xbm = ws;                       // 4M  [b*2048+t][d]
  u16* Wkb = xbm + 4194304;            // 1M  (head-outer rows)
  u16* Wvb = Wkb + 1048576;            // 1M  (head-outer rows)
  u16* Wqb = Wvb + 1048576;            // 1M  (head-outer rows, pre-scaled)
  u16* Wob = Wqb + 1048576;            // 1M  (unpermuted)
  u16* Qh  = Wob + 1048576;            // 4M  [bh][t][64]
  u16* Kh  = Qh  + 4194304;            // 4M  [bh][t][64]
  u16* Vt  = Kh  + 4194304;            // 4M  [bh][64][t]
  u16* Aout= Vt  + 4194304;            // 4M  [b*2048+t][h*64+dp]

  cast_all<<<8192, 256, 0, stream>>>(x, Wk, Wv, Wq, Wo, ws);

  // QKV: z=0 Q, z=1 K, z=2 V (swapped -> V^T directly)
  gemm_bt<<<dim3(8, 32, 3), 256, 0, stream>>>(
      xbm, Wqb, Wkb, Wvb, (void*)Qh, (void*)Kh, (void*)Vt, 0);

  attn_fwd<<<512, 256, 0, stream>>>(Qh, Kh, Vt, Aout);

  // output projection -> f32 d_out (rows un-permuted to [t][b])
  gemm_bt<<<dim3(8, 32, 1), 256, 0, stream>>>(
      Aout, Wob, nullptr, nullptr, d_out, nullptr, nullptr, 2);
}

// Round 5
// 113.346 us; speedup vs baseline: 3.0334x; 1.1092x over previous
//
#include <hip/hip_runtime.h>

// ---------------- problem constants ----------------
#define T_LEN   2048
#define BATCH   2
#define DMODEL  1024
#define NHEAD   16
#define DHEAD   64
#define MROWS   4096          // T*B
#define KDIM    1024
#define NDIM    1024
#define ATT_SC2 (0.125f * 1.44269504088896f)   // SCALE * log2(e), folded into Wq

typedef unsigned short u16;
typedef unsigned int   u32;
typedef u16   u16x8 __attribute__((ext_vector_type(8)));
typedef u16   u16x4 __attribute__((ext_vector_type(4)));
typedef __bf16 bf16x8 __attribute__((ext_vector_type(8)));
typedef float f32x4 __attribute__((ext_vector_type(4)));

__device__ __forceinline__ u16 f2bf(float f) {
  u32 u = __builtin_bit_cast(u32, f);
  u += 0x7fffu + ((u >> 16) & 1u);           // round-to-nearest-even
  return (u16)(u >> 16);
}

__device__ __forceinline__ u16 bfc(float f) {  // compiler cvt (packs to cvt_pk)
  return __builtin_bit_cast(u16, (__bf16)f);
}

__device__ __forceinline__ f32x4 mfma16(u16x8 a, u16x8 b, f32x4 c) {
  return __builtin_amdgcn_mfma_f32_16x16x32_bf16(
      __builtin_bit_cast(bf16x8, a), __builtin_bit_cast(bf16x8, b), c, 0, 0, 0);
}

__device__ __forceinline__ void gload16(const u16* g, u16* l) {
  __builtin_amdgcn_global_load_lds((const __attribute__((address_space(1))) void*)g,
                                   (__attribute__((address_space(3))) void*)l,
                                   16, 0, 0);
}

// ---------------- cast f32 -> bf16 with layout fixes ----------------
// ws (u16): [xbm 4M][Wqkv 3M: rows 0..1023 Wq | 1024..2047 Wk | 2048..3071 Wv]
//           [Wob 1M][Qh 4M][Kh 4M][Vt 4M][Aout 4M]
// xbm: x[t][b][d] -> [b*2048+t][d]; W rows head-perm u=dp*16+h -> h*64+dp;
// Wq pre-scaled by SCALE*log2e.
#define XN 4194304u
__global__ __launch_bounds__(256) void cast_all(
    const float* __restrict__ x,  const float* __restrict__ wk,
    const float* __restrict__ wv, const float* __restrict__ wq,
    const float* __restrict__ wo, u16* __restrict__ ws) {
  size_t i = ((size_t)blockIdx.x * 256 + threadIdx.x) * 4;
  const float* src; size_t soff, doff; float sc = 1.0f;
  if (i < XN) {
    int m = (int)(i >> 10), d = (int)(i & 1023);
    int t = m >> 1, b = m & 1;
    src = x; soff = i;
    doff = ((size_t)(b * 2048 + t) << 10) + d;
  } else {
    size_t off = i - XN;
    int wi = (int)(off >> 20);
    off &= 1048575u;
    int u = (int)(off >> 10), c = (int)(off & 1023);
    src = (wi == 0) ? wk : (wi == 1) ? wv : (wi == 2) ? wq : wo;
    soff = off;
    if (wi == 3) {
      doff = XN + 3u * 1048576u + off;                      // Wob linear
    } else {
      int slot = (wi == 2) ? 0 : (wi == 0) ? 1 : 2;         // Q,K,V pack order
      int up = (u & 15) * 64 + (u >> 4);                    // head-outer perm
      doff = XN + (size_t)slot * 1048576u + ((size_t)up << 10) + c;
      if (wi == 2) sc = ATT_SC2;
    }
  }
  float4 v = *reinterpret_cast<const float4*>(src + soff);
  u16x4 o;
  o.s0 = f2bf(v.x * sc); o.s1 = f2bf(v.y * sc); o.s2 = f2bf(v.z * sc); o.s3 = f2bf(v.w * sc);
  *reinterpret_cast<u16x4*>(ws + doff) = o;
}

// ---------------- QKV GEMM: 256x128 tile, BK=64, per-wave 128x64 ----------------
// 384 blocks: wgid<256 -> QK (A=xbm M=4096, W=Wqkv[0:2048) N=2048)
//             wgid>=256 -> V swapped (A=Wv rows M=1024, W=xbm N=4096)
// XCD swizzle: xcd = blk%8 owns wgid chunk [xcd*48, xcd*48+48).
__global__ __launch_bounds__(256, 2) void gemm_qkv(
    const u16* __restrict__ xbm, const u16* __restrict__ Wqkv,
    u16* __restrict__ Qh, u16* __restrict__ Kh, u16* __restrict__ Vt) {
  __shared__ __align__(16) u16 As[256 * 64];   // 32 KB
  __shared__ __align__(16) u16 Bs[128 * 64];   // 16 KB

  const int tid = threadIdx.x;
  const int l  = tid & 63, w = tid >> 6;
  const int lr = l & 15,  lg = l >> 4;
  const int wm = w >> 1,  wn = w & 1;

  const int blk  = blockIdx.x;
  const int wgid = (blk & 7) * 48 + (blk >> 3);   // bijective (384 % 8 == 0)

  const u16 *A, *W;
  int m0, n0, isV;
  if (wgid < 256) {                 // QK: same-bx (weight panel) grouped per XCD
    const int bx = wgid >> 4, by = wgid & 15;
    A = xbm; W = Wqkv; m0 = by * 256; n0 = bx * 128; isV = 0;
  } else {                          // V swapped
    const int v = wgid - 256;
    const int vby = v >> 5, vbx = v & 31;
    A = Wqkv + (2048u << 10); W = xbm; m0 = vby * 256; n0 = vbx * 128; isV = 1;
  }

  f32x4 acc[8][4];
#pragma unroll
  for (int i = 0; i < 8; ++i)
#pragma unroll
    for (int j = 0; j < 4; ++j) acc[i][j] = (f32x4)(0.0f);

  for (int k0 = 0; k0 < KDIM; k0 += 64) {
    // stage A (256x64, 2048 chunks) + B (128x64, 1024 chunks), XOR-swizzled
#pragma unroll
    for (int i = 0; i < 8; ++i) {
      const int base = i * 256 + w * 64;         // wave-uniform chunk base
      const int p = base + l;
      const int r = p >> 3, c = p & 7;
      gload16(A + (size_t)(m0 + r) * KDIM + k0 + ((c ^ (r & 7)) << 3),
              As + (size_t)base * 8);
    }
#pragma unroll
    for (int i = 0; i < 4; ++i) {
      const int base = i * 256 + w * 64;
      const int p = base + l;
      const int r = p >> 3, c = p & 7;
      gload16(W + (size_t)(n0 + r) * KDIM + k0 + ((c ^ (r & 7)) << 3),
              Bs + (size_t)base * 8);
    }
    __syncthreads();

#pragma unroll
    for (int ks = 0; ks < 2; ++ks) {
      const int cr = ks * 4 + lg;
      u16x8 bf_[4];
#pragma unroll
      for (int ni = 0; ni < 4; ++ni) {
        const int rr = wn * 64 + ni * 16 + lr;
        bf_[ni] = *reinterpret_cast<const u16x8*>(Bs + rr * 64 + ((cr ^ (rr & 7)) << 3));
      }
      __builtin_amdgcn_s_setprio(1);
#pragma unroll
      for (int mi = 0; mi < 8; ++mi) {
        const int rr = wm * 128 + mi * 16 + lr;
        const u16x8 af = *reinterpret_cast<const u16x8*>(
            As + rr * 64 + ((cr ^ (rr & 7)) << 3));
#pragma unroll
        for (int ni = 0; ni < 4; ++ni)
          acc[mi][ni] = mfma16(af, bf_[ni], acc[mi][ni]);
      }
      __builtin_amdgcn_s_setprio(0);
    }
    __syncthreads();
  }

  // epilogue
#pragma unroll
  for (int mi = 0; mi < 8; ++mi)
#pragma unroll
    for (int ni = 0; ni < 4; ++ni)
#pragma unroll
      for (int r = 0; r < 4; ++r) {
        const int row = m0 + wm * 128 + mi * 16 + lg * 4 + r;
        const int col = n0 + wn * 64 + ni * 16 + lr;
        const u16 v = bfc(acc[mi][ni][r]);
        if (!isV) {
          // row = b*2048+t ; col in [0,2048): sec 0=Q 1=K, c=h*64+dp
          const int bb = row >> 11, t = row & 2047;
          const int c = col & 1023, hh = c >> 6, dp = c & 63;
          u16* d = (col < 1024) ? Qh : Kh;
          d[(((size_t)(bb * NHEAD + hh) << 11) + t) * 64 + dp] = v;
        } else {
          // row = h*64+dp (Wv head-perm'd); col = b*2048+t
          const int hh = row >> 6, dp = row & 63;
          const int bb = col >> 11, t = col & 2047;
          Vt[((((size_t)(bb * NHEAD + hh)) * 64 + dp) << 11) + t] = v;
        }
      }
}

// ---------------- O projection: C = A * Wo^T, 128x128 tile ----------------
__global__ __launch_bounds__(256) void gemm_o(
    const u16* __restrict__ A, const u16* __restrict__ W, float* __restrict__ out) {
  __shared__ __align__(16) u16 As[128 * 64];
  __shared__ __align__(16) u16 Bs[128 * 64];

  const int tid = threadIdx.x;
  const int l  = tid & 63, w = tid >> 6;
  const int lr = l & 15,  lg = l >> 4;
  const int wm = w >> 1,  wn = w & 1;
  const int m0 = blockIdx.y * 128;
  const int n0 = blockIdx.x * 128;

  f32x4 acc[4][4];
#pragma unroll
  for (int i = 0; i < 4; ++i)
#pragma unroll
    for (int j = 0; j < 4; ++j) acc[i][j] = (f32x4)(0.0f);

  for (int k0 = 0; k0 < KDIM; k0 += 64) {
#pragma unroll
    for (int i = 0; i < 4; ++i) {
      int p  = i * 256 + tid;
      int r  = p >> 3, cph = p & 7;
      int cl = cph ^ (r & 7);
      u16* ldsA = As + (size_t)(i * 256 + w * 64) * 8;
      u16* ldsB = Bs + (size_t)(i * 256 + w * 64) * 8;
      gload16(A + (size_t)(m0 + r) * KDIM + k0 + cl * 8, ldsA);
      gload16(W + (size_t)(n0 + r) * KDIM + k0 + cl * 8, ldsB);
    }
    __syncthreads();

#pragma unroll
    for (int ks = 0; ks < 2; ++ks) {
      u16x8 af[4], bf_[4];
      const int cr = ks * 4 + lg;
#pragma unroll
      for (int mi = 0; mi < 4; ++mi) {
        int rr = wm * 64 + mi * 16 + lr;
        af[mi] = *reinterpret_cast<const u16x8*>(As + rr * 64 + ((cr ^ (rr & 7)) * 8));
      }
#pragma unroll
      for (int ni = 0; ni < 4; ++ni) {
        int rr = wn * 64 + ni * 16 + lr;
        bf_[ni] = *reinterpret_cast<const u16x8*>(Bs + rr * 64 + ((cr ^ (rr & 7)) * 8));
      }
#pragma unroll
      for (int mi = 0; mi < 4; ++mi)
#pragma unroll
        for (int ni = 0; ni < 4; ++ni)
          acc[mi][ni] = mfma16(af[mi], bf_[ni], acc[mi][ni]);
    }
    __syncthreads();
  }

#pragma unroll
  for (int mi = 0; mi < 4; ++mi)
#pragma unroll
    for (int ni = 0; ni < 4; ++ni)
#pragma unroll
      for (int r = 0; r < 4; ++r) {
        int row = m0 + wm * 64 + mi * 16 + lg * 4 + r;   // b*2048+t
        int col = n0 + wn * 64 + ni * 16 + lr;
        int t = row & 2047, bb = row >> 11;
        out[((size_t)(t * 2 + bb) << 10) + col] = acc[mi][ni][r];
      }
}

// ---------------- causal flash attention v4 ----------------
__global__ __launch_bounds__(256) void attn_fwd(
    const u16* __restrict__ Qh, const u16* __restrict__ Kh,
    const u16* __restrict__ Vt, u16* __restrict__ Aout) {
  __shared__ __align__(16) u16 Ks[2][8192];   // [128 kv][64 d], chunk^ (r&7)
  __shared__ __align__(16) u16 Vs[2][8192];   // [64 d][128 kv], chunk^ (r&15)
  __shared__ __align__(16) u16 Pl[4][1024];   // per-wave [16 q][64 kv], chunk^(lr&7)

  const int tid = threadIdx.x;
  const int l = tid & 63, w = tid >> 6;
  const int lr = l & 15, lg = l >> 4;
  const int blk = blockIdx.x;
  const int bxx = (blk >> 3) & 15;
  const int bh  = ((blk >> 7) << 3) + (blk & 7);
  const int b = bh >> 4, h = bh & 15;

  const u16* kg = Kh + ((size_t)bh << 17);    // [t][64]
  const u16* vg = Vt + ((size_t)bh << 17);    // [64][2048]

  const u16x8 ones = {0x3F80,0x3F80,0x3F80,0x3F80,0x3F80,0x3F80,0x3F80,0x3F80};

  auto stage = [&](int buf, int kv0) {
#pragma unroll
    for (int j = 0; j < 4; ++j) {
      const int base = (j * 4 + w) * 64;       // chunk base (wave-uniform)
      const int g = base + l;
      const int rk = g >> 3, ck = g & 7;       // K: 8 chunks/row
      gload16(kg + (size_t)(kv0 + rk) * 64 + ((ck ^ (rk & 7)) << 3),
              &Ks[buf][(size_t)base * 8]);
      const int rv = g >> 4, cv = g & 15;      // V: 16 chunks/row
      gload16(vg + ((size_t)rv << 11) + kv0 + ((cv ^ (rv & 15)) << 3),
              &Vs[buf][(size_t)base * 8]);
    }
  };

  for (int ph = 0; ph < 2; ++ph) {
    const int qb = ph ? bxx : 31 - bxx;
    const int qbase = qb * 64 + w * 16;
    const int qrow = qbase + lr;

    const u16* qptr = Qh + (((size_t)bh << 11) + qrow) * 64 + lg * 8;
    const u16x8 qf0 = *reinterpret_cast<const u16x8*>(qptr);
    const u16x8 qf1 = *reinterpret_cast<const u16x8*>(qptr + 32);

    f32x4 oacc[4];
#pragma unroll
    for (int i = 0; i < 4; ++i) oacc[i] = (f32x4)(0.0f);
    f32x4 sum4 = (f32x4)(0.0f);
    float m_ = -1e30f;

    const int npair = (qb + 2) >> 1;
    stage(0, 0);
    __syncthreads();

    int cur = 0;
    for (int t = 0; t < npair; ++t) {
      const int kv0 = t * 128;
      if (t + 1 < npair) stage(cur ^ 1, kv0 + 128);

      float p[2][4][4];
      __builtin_amdgcn_s_setprio(1);
#pragma unroll
      for (int hh = 0; hh < 2; ++hh) {
        const int i64 = 2 * t + hh;
        if (i64 <= qb) {
#pragma unroll
          for (int tt = 0; tt < 4; ++tt) {
            const int row = hh * 64 + tt * 16 + lr;
            const u16x8 kf0 = *reinterpret_cast<const u16x8*>(
                &Ks[cur][row * 64 + ((lg ^ (row & 7)) << 3)]);
            const u16x8 kf1 = *reinterpret_cast<const u16x8*>(
                &Ks[cur][row * 64 + (((4 + lg) ^ (row & 7)) << 3)]);
            f32x4 sacc = (f32x4)(0.0f);
            sacc = mfma16(kf0, qf0, sacc);
            sacc = mfma16(kf1, qf1, sacc);
#pragma unroll
            for (int r = 0; r < 4; ++r) p[hh][tt][r] = sacc[r];
          }
          if (i64 == qb) {
#pragma unroll
            for (int tt = 0; tt < 4; ++tt)
#pragma unroll
              for (int r = 0; r < 4; ++r) {
                const int kv = kv0 + hh * 64 + tt * 16 + lg * 4 + r;
                if (kv > qrow) p[hh][tt][r] = -1e30f;
              }
          }
        } else {
#pragma unroll
          for (int tt = 0; tt < 4; ++tt)
#pragma unroll
            for (int r = 0; r < 4; ++r) p[hh][tt][r] = -1e30f;
        }
      }
      __builtin_amdgcn_s_setprio(0);

      float mx = p[0][0][0];
#pragma unroll
      for (int hh = 0; hh < 2; ++hh)
#pragma unroll
        for (int tt = 0; tt < 4; ++tt)
#pragma unroll
          for (int r = 0; r < 4; ++r) mx = fmaxf(mx, p[hh][tt][r]);
      mx = fmaxf(mx, __shfl_xor(mx, 16, 64));
      mx = fmaxf(mx, __shfl_xor(mx, 32, 64));

      if (__any(mx > m_ + 8.0f)) {
        const float mnew = fmaxf(m_, mx);
        const float al = __builtin_amdgcn_exp2f(m_ - mnew);
        m_ = mnew;
#pragma unroll
        for (int r = 0; r < 4; ++r) {
          const float ab = __shfl(al, lg * 4 + r, 64);
          sum4[r] *= ab;
          oacc[0][r] *= ab; oacc[1][r] *= ab; oacc[2][r] *= ab; oacc[3][r] *= ab;
        }
      }

#pragma unroll
      for (int hh = 0; hh < 2; ++hh)
#pragma unroll
        for (int tt = 0; tt < 4; ++tt)
#pragma unroll
          for (int r = 0; r < 4; ++r)
            p[hh][tt][r] = __builtin_amdgcn_exp2f(p[hh][tt][r] - m_);

#pragma unroll
      for (int kvh = 0; kvh < 2; ++kvh) {
#pragma unroll
        for (int tt = 0; tt < 4; ++tt) {
          u16x4 pk;
          pk.s0 = bfc(p[kvh][tt][0]); pk.s1 = bfc(p[kvh][tt][1]);
          pk.s2 = bfc(p[kvh][tt][2]); pk.s3 = bfc(p[kvh][tt][3]);
          *reinterpret_cast<u16x4*>(
              &Pl[w][lr * 64 + (((tt * 2 + (lg >> 1)) ^ (lr & 7)) << 3)
                     + ((lg & 1) << 2)]) = pk;
        }
        __builtin_amdgcn_s_setprio(1);
#pragma unroll
        for (int kh = 0; kh < 2; ++kh) {
          const u16x8 pa = *reinterpret_cast<const u16x8*>(
              &Pl[w][lr * 64 + (((kh * 4 + lg) ^ (lr & 7)) << 3)]);
          sum4 = mfma16(pa, ones, sum4);
#pragma unroll
          for (int ni = 0; ni < 4; ++ni) {
            const int dr = ni * 16 + lr;
            const int ck = kvh * 8 + kh * 4 + lg;
            const u16x8 vf = *reinterpret_cast<const u16x8*>(
                &Vs[cur][dr * 128 + ((ck ^ (dr & 15)) << 3)]);
            oacc[ni] = mfma16(pa, vf, oacc[ni]);
          }
        }
        __builtin_amdgcn_s_setprio(0);
      }

      __syncthreads();
      cur ^= 1;
    }

#pragma unroll
    for (int r = 0; r < 4; ++r) {
      const float inv = 1.0f / sum4[r];
      const int q = qbase + lg * 4 + r;
      const size_t rowbase = (((size_t)(b * 2048 + q)) << 10) + h * DHEAD;
#pragma unroll
      for (int ni = 0; ni < 4; ++ni)
        Aout[rowbase + ni * 16 + lr] = bfc(oacc[ni][r] * inv);
    }
  }
}

// ---------------- launch ----------------
extern "C" void kernel_launch(void* const* d_in, const int* in_sizes, int n_in,
                              void* d_out, int out_size, void* d_ws, size_t ws_size,
                              hipStream_t stream) {
  const float* x  = (const float*)d_in[0];
  const float* Wk = (const float*)d_in[1];
  const float* Wv = (const float*)d_in[2];
  const float* Wq = (const float*)d_in[3];
  const float* Wo = (const float*)d_in[4];
  // d_in[5] = mask (causal, known structurally)

  u16* ws   = (u16*)d_ws;
  u16* xbm  = ws;                      // 4M  [b*2048+t][d]
  u16* Wqkv = xbm + 4194304;           // 3M  [Wq|Wk|Wv], head-perm rows
  u16* Wob  = Wqkv + 3145728;          // 1M
  u16* Qh   = Wob + 1048576;           // 4M  [bh][t][64]
  u16* Kh   = Qh  + 4194304;           // 4M  [bh][t][64]
  u16* Vt   = Kh  + 4194304;           // 4M  [bh][64][t]
  u16* Aout = Vt  + 4194304;           // 4M  [b*2048+t][h*64+dp]

  cast_all<<<8192, 256, 0, stream>>>(x, Wk, Wv, Wq, Wo, ws);

  gemm_qkv<<<384, 256, 0, stream>>>(xbm, Wqkv, Qh, Kh, Vt);

  attn_fwd<<<512, 256, 0, stream>>>(Qh, Kh, Vt, Aout);

  gemm_o<<<dim3(8, 32), 256, 0, stream>>>(Aout, Wob, (float*)d_out);
}